// Round 6
// baseline (377.204 us; speedup 1.0000x reference)
//
#include <hip/hip_runtime.h>
#include <cstddef>
#include <cstdint>

#define VOCAB 32000
#define EMB 32
#define HID 64
#define NG 256      // 4*HID
#define BATCH 1024
#define SEQ 512
#define NB 4        // real batch rows per block, mapped to M-rows 0,4,8,12
#define ROWB 72     // halfs per H row: 64 + 8 pad (row stride 144 B)
#define PFD 8       // xg gather prefetch depth (steps ahead)
#define SEQP (SEQ + PFD)

#define L2E 1.44269504088896340736f  // log2(e)

typedef short short8 __attribute__((ext_vector_type(8)));
typedef _Float16 half8 __attribute__((ext_vector_type(8)));
typedef float floatx4 __attribute__((ext_vector_type(4)));
typedef int int4v __attribute__((ext_vector_type(4)));

union FragH {
  half8 h;
  int4v v;
};

// ---------------- Kernel 1: fused embedding+input-proj table ----------------
// GATE-INTERLEAVED layout: table[v*256 + h*4 + g], g in {i,f,g,o}.
// exp2-FOLDING: stored preactivation is PRE-SCALED per gate type:
//   i,f,o rows: * -log2(e)   (sigmoid(x) = rcp(1+exp2(-L2E*x)))
//   g   row  : * +2log2(e)   (tanh(x)    = 1-2*rcp(exp2(2*L2E*x)+1))
#define K1_ROWS 32
__global__ __launch_bounds__(256) void build_table(
    const float* __restrict__ emb, const float* __restrict__ W_ih,
    const float* __restrict__ b_ih, const float* __restrict__ b_hh,
    float* __restrict__ table) {
  __shared__ __align__(16) float erow[K1_ROWS * EMB];
  const int tid = threadIdx.x;
  const int v0 = blockIdx.x * K1_ROWS;
  const int gidx = (tid & 3) * 64 + (tid >> 2);  // W_ih row this thread owns
  const float sc = ((tid & 3) == 2) ? (2.0f * L2E) : (-L2E);  // per-gate scale

  float w[EMB];
#pragma unroll
  for (int e = 0; e < EMB; e += 4) {
    const float4 t = *(const float4*)&W_ih[gidx * EMB + e];
    w[e] = t.x; w[e + 1] = t.y; w[e + 2] = t.z; w[e + 3] = t.w;
  }
  const float bsum = b_ih[gidx] + b_hh[gidx];

  ((float4*)erow)[tid] = ((const float4*)&emb[(size_t)v0 * EMB])[tid];
  __syncthreads();

#pragma unroll 4
  for (int r = 0; r < K1_ROWS; ++r) {
    float acc = bsum;
#pragma unroll
    for (int e = 0; e < EMB; ++e) acc += erow[r * EMB + e] * w[e];
    table[(size_t)(v0 + r) * NG + tid] = acc * sc;  // coalesced; layout h*4+g
  }
}

// ---------------- Kernel 2: LSTM recurrence via MFMA (fp16 single-product) --
// Grid: BATCH/NB = 256 blocks x 256 threads (4 waves), 1 block/CU, 1 wave/SIMD
// -> pure latency; wall = SEQ x step-critical-path.
// Best measured form (R1, 147us): xg folded into the MFMA C-operand, 2-chain
// MFMA per gate group. This version keeps that but builds a FRESH c-tuple per
// step (z4-based) so there is no cross-step MFMA register dependency (R3's
// regression) and no post-MFMA adds at the chain tail (R5's regression).
__global__ __launch_bounds__(256, 1) void lstm_mfma(
    const int* __restrict__ x, const float* __restrict__ table,
    const float* __restrict__ W_hh, float* __restrict__ h_out) {
  __shared__ __align__(16) _Float16 Hs[2][16 * ROWB];  // [buf][row][hid]
  __shared__ int xls[NB * SEQP];                       // byte offsets, padded

  const int tid = threadIdx.x;
  const int w = tid >> 6;       // wave 0..3
  const int lane = tid & 63;
  const int quad = lane >> 4;   // 0..3 -> owns batch row blk*4+quad (M-row 4*quad)
  const int col = lane & 15;    // MFMA n-col / A m-row
  const int blk = blockIdx.x;
  const int myhid = w * 16 + col;

  // zero H buffers (junk rows read as A must be exactly zero)
  {
    int* hz = (int*)&Hs[0][0];
    const int nz = (int)(sizeof(Hs) / 4);
    for (int i = tid; i < nz; i += 256) hz[i] = 0;
  }
  // stage this block's token ids as pre-shifted byte offsets, with PFD pad
  {
    const int* xsrc = &x[(size_t)blk * NB * SEQ];
    for (int i = tid; i < NB * SEQ; i += 256) {
      const int q = i >> 9;          // SEQ = 512
      const int t = i & (SEQ - 1);
      xls[q * SEQP + t] = xsrc[i] << 10;  // *NG*sizeof(float)
    }
    if (tid < NB * PFD) {
      const int q = tid >> 3;        // PFD = 8
      const int t = tid & (PFD - 1);
      xls[q * SEQP + SEQ + t] = xsrc[q * SEQ + SEQ - 1] << 10;
    }
  }

  // resident W_hh fragments (fp16, PRE-SCALED per gate type ti):
  // B[k][n], n = (w+ti*4)*16+col, k = ko*32+quad*8+j
  FragH Bf[4][2];
#pragma unroll
  for (int ti = 0; ti < 4; ++ti) {
    const int n = (w + ti * 4) * 16 + col;
    const float sc = (ti == 2) ? (2.0f * L2E) : (-L2E);
#pragma unroll
    for (int ko = 0; ko < 2; ++ko) {
      const float* src = &W_hh[n * HID + ko * 32 + quad * 8];
#pragma unroll
      for (int j = 0; j < 8; ++j) Bf[ti][ko].h[j] = (_Float16)(src[j] * sc);
    }
  }

  const floatx4 z4 = (floatx4){0.f, 0.f, 0.f, 0.f};

  float cs = 0.0f, hcur = 0.0f;  // cs = 2*L2E * c (scaled cell state)

  __syncthreads();  // xls/Hs visible (full drain OK here, once)

  const int xrow = quad * SEQP;
  const char* __restrict__ tb4 = (const char*)(table + (size_t)myhid * 4);

  auto gather = [&](int tt) -> floatx4 {
    return *(const floatx4*)(tb4 + xls[xrow + tt]);
  };

  // prologue: fill the 8-deep prefetch pipeline
  floatx4 xg0 = gather(0), xg1 = gather(1), xg2 = gather(2), xg3 = gather(3);
  floatx4 xg4 = gather(4), xg5 = gather(5), xg6 = gather(6), xg7 = gather(7);

  auto step = [&](floatx4& XG, const int RB, const int TT) {
    // fold the PFD-step-old xg into fresh C-operands (element 0 only; junk
    // rows stay 0 because A junk rows are 0 and C[1..3]=0), then re-issue
    // this register set's gather for step TT+PFD
    floatx4 c0 = z4, c1 = z4, c2 = z4, c3 = z4;
    c0[0] = XG[0]; c1[0] = XG[1]; c2[0] = XG[2]; c3[0] = XG[3];
    XG = gather(TT + PFD);  // padded xls: no clamp needed

    // A fragments: A[m=col][k = ko*32 + quad*8 + j]
    const int abase = col * ROWB + quad * 8;
    FragH A0, A1;
    A0.v = *(const int4v*)&Hs[RB][abase];
    A1.v = *(const int4v*)&Hs[RB][abase + 32];

    floatx4 r0 = __builtin_amdgcn_mfma_f32_16x16x32_f16(A0.h, Bf[0][0].h, c0, 0, 0, 0);
    r0 = __builtin_amdgcn_mfma_f32_16x16x32_f16(A1.h, Bf[0][1].h, r0, 0, 0, 0);
    floatx4 r1 = __builtin_amdgcn_mfma_f32_16x16x32_f16(A0.h, Bf[1][0].h, c1, 0, 0, 0);
    r1 = __builtin_amdgcn_mfma_f32_16x16x32_f16(A1.h, Bf[1][1].h, r1, 0, 0, 0);
    floatx4 r2 = __builtin_amdgcn_mfma_f32_16x16x32_f16(A0.h, Bf[2][0].h, c2, 0, 0, 0);
    r2 = __builtin_amdgcn_mfma_f32_16x16x32_f16(A1.h, Bf[2][1].h, r2, 0, 0, 0);
    floatx4 r3 = __builtin_amdgcn_mfma_f32_16x16x32_f16(A0.h, Bf[3][0].h, c3, 0, 0, 0);
    r3 = __builtin_amdgcn_mfma_f32_16x16x32_f16(A1.h, Bf[3][1].h, r3, 0, 0, 0);

    // gates, exp2-folded (preacts pre-scaled; see build_table)
    {
      const float gi = __builtin_amdgcn_rcpf(1.0f + __builtin_amdgcn_exp2f(r0[0]));
      const float gf = __builtin_amdgcn_rcpf(1.0f + __builtin_amdgcn_exp2f(r1[0]));
      const float rg = __builtin_amdgcn_rcpf(1.0f + __builtin_amdgcn_exp2f(r2[0]));
      const float go = __builtin_amdgcn_rcpf(1.0f + __builtin_amdgcn_exp2f(r3[0]));
      const float gg2 = fmaf(-4.0f * L2E, rg, 2.0f * L2E);
      cs = fmaf(gi, gg2, gf * cs);  // scaled cell state
      const float rc = __builtin_amdgcn_rcpf(1.0f + __builtin_amdgcn_exp2f(cs));
      hcur = go * fmaf(-2.0f, rc, 1.0f);  // go * tanh(c), unscaled
      Hs[RB ^ 1][(quad * 4) * ROWB + myhid] = (_Float16)hcur;  // M-row 4*quad
    }
    // RAW barrier: drain LDS only; global prefetch loads stay in flight.
    asm volatile("s_waitcnt lgkmcnt(0)\n\ts_barrier" ::: "memory");
  };

  for (int t = 0; t < SEQ; t += 8) {
    step(xg0, 0, t);
    step(xg1, 1, t + 1);
    step(xg2, 0, t + 2);
    step(xg3, 1, t + 3);
    step(xg4, 0, t + 4);
    step(xg5, 1, t + 5);
    step(xg6, 0, t + 6);
    step(xg7, 1, t + 7);
  }

  h_out[((size_t)blk * NB + quad) * HID + myhid] = hcur;
}

// ---------------- Kernel 3: FC to vocab via MFMA (fp16 hi/lo, ~fp32 acc) ----
// out[1024 x 32000] = h[1024 x 64] @ fc_W^T + b. Grid: 250 blocks x 256 thr.
// Each block: 128 vocab cols; wave w owns 32 cols (2 N-tiles of 16).
// fp16 hi/lo error compensation: X = Xh + Xl (both fp16);
//   out = Ah*Bh + Al*Bh + Ah*Bl  (Al*Bl ~ 2^-22, dropped) -> fp32-level acc.
// B fragments resident in regs (fc_W tile read ONCE per block); no LDS.
// M streamed in 64 chunks of 16 batch rows, 1-chunk h-load lookahead.
#define FCV 128
__global__ __launch_bounds__(256, 1) void fc_mfma(
    const float* __restrict__ h, const float* __restrict__ fc_W,
    const float* __restrict__ fc_b, float* __restrict__ out) {
  const int tid = threadIdx.x;
  const int w = tid >> 6;
  const int lane = tid & 63;
  const int q = lane >> 4;
  const int c = lane & 15;
  const int nbase = blockIdx.x * FCV + w * 32;  // + nt*16 + c

  const floatx4 z4 = (floatx4){0.f, 0.f, 0.f, 0.f};

  // resident B fragments: B[k=ko*32+q*8+j][n=nbase+nt*16+c] = fc_W[n][k]
  FragH Bh[2][2], Bl[2][2];
#pragma unroll
  for (int nt = 0; nt < 2; ++nt) {
#pragma unroll
    for (int ko = 0; ko < 2; ++ko) {
      const float* src = &fc_W[(size_t)(nbase + nt * 16 + c) * HID + ko * 32 + q * 8];
#pragma unroll
      for (int j = 0; j < 8; ++j) {
        const float f = src[j];
        const _Float16 hi = (_Float16)f;
        Bh[nt][ko].h[j] = hi;
        Bl[nt][ko].h[j] = (_Float16)(f - (float)hi);
      }
    }
  }
  const float bias0 = fc_b[nbase + c];
  const float bias1 = fc_b[nbase + 16 + c];

  // A-chunk loader: lane (q,c) reads h[row=mc*16+c][k=q*8..+7, +32..]
  auto loadh = [&](int mc, floatx4& a0, floatx4& a1, floatx4& a2, floatx4& a3) {
    const float* hr = &h[(size_t)(mc * 16 + c) * HID + q * 8];
    a0 = *(const floatx4*)hr;
    a1 = *(const floatx4*)(hr + 4);
    a2 = *(const floatx4*)(hr + 32);
    a3 = *(const floatx4*)(hr + 36);
  };

  floatx4 p0, p1, p2, p3, n0, n1, n2, n3;
  loadh(0, p0, p1, p2, p3);

  for (int mc = 0; mc < BATCH / 16; ++mc) {
    if (mc + 1 < BATCH / 16) loadh(mc + 1, n0, n1, n2, n3);

    // build A fragments (hi/lo) from the prefetched chunk
    FragH Ah0, Al0, Ah1, Al1;
#pragma unroll
    for (int j = 0; j < 4; ++j) {
      float f = p0[j];
      _Float16 hi = (_Float16)f;
      Ah0.h[j] = hi; Al0.h[j] = (_Float16)(f - (float)hi);
      f = p1[j]; hi = (_Float16)f;
      Ah0.h[4 + j] = hi; Al0.h[4 + j] = (_Float16)(f - (float)hi);
      f = p2[j]; hi = (_Float16)f;
      Ah1.h[j] = hi; Al1.h[j] = (_Float16)(f - (float)hi);
      f = p3[j]; hi = (_Float16)f;
      Ah1.h[4 + j] = hi; Al1.h[4 + j] = (_Float16)(f - (float)hi);
    }

    // two independent 6-chain MFMA accumulations (nt = 0, 1)
    floatx4 acc0 = __builtin_amdgcn_mfma_f32_16x16x32_f16(Ah0.h, Bh[0][0].h, z4, 0, 0, 0);
    floatx4 acc1 = __builtin_amdgcn_mfma_f32_16x16x32_f16(Ah0.h, Bh[1][0].h, z4, 0, 0, 0);
    acc0 = __builtin_amdgcn_mfma_f32_16x16x32_f16(Ah1.h, Bh[0][1].h, acc0, 0, 0, 0);
    acc1 = __builtin_amdgcn_mfma_f32_16x16x32_f16(Ah1.h, Bh[1][1].h, acc1, 0, 0, 0);
    acc0 = __builtin_amdgcn_mfma_f32_16x16x32_f16(Al0.h, Bh[0][0].h, acc0, 0, 0, 0);
    acc1 = __builtin_amdgcn_mfma_f32_16x16x32_f16(Al0.h, Bh[1][0].h, acc1, 0, 0, 0);
    acc0 = __builtin_amdgcn_mfma_f32_16x16x32_f16(Al1.h, Bh[0][1].h, acc0, 0, 0, 0);
    acc1 = __builtin_amdgcn_mfma_f32_16x16x32_f16(Al1.h, Bh[1][1].h, acc1, 0, 0, 0);
    acc0 = __builtin_amdgcn_mfma_f32_16x16x32_f16(Ah0.h, Bl[0][0].h, acc0, 0, 0, 0);
    acc1 = __builtin_amdgcn_mfma_f32_16x16x32_f16(Ah0.h, Bl[1][0].h, acc1, 0, 0, 0);
    acc0 = __builtin_amdgcn_mfma_f32_16x16x32_f16(Ah1.h, Bl[0][1].h, acc0, 0, 0, 0);
    acc1 = __builtin_amdgcn_mfma_f32_16x16x32_f16(Ah1.h, Bl[1][1].h, acc1, 0, 0, 0);

    // store: C/D layout col=lane&15, row=(lane>>4)*4+reg
#pragma unroll
    for (int r = 0; r < 4; ++r) {
      const size_t row = (size_t)(mc * 16 + q * 4 + r) * VOCAB;
      __builtin_nontemporal_store(acc0[r] + bias0, &out[row + nbase + c]);
      __builtin_nontemporal_store(acc1[r] + bias1, &out[row + nbase + 16 + c]);
    }

    p0 = n0; p1 = n1; p2 = n2; p3 = n3;
  }
}

extern "C" void kernel_launch(void* const* d_in, const int* in_sizes, int n_in,
                              void* d_out, int out_size, void* d_ws, size_t ws_size,
                              hipStream_t stream) {
  const int* x = (const int*)d_in[0];
  const float* emb = (const float*)d_in[1];
  const float* W_ih = (const float*)d_in[2];
  const float* W_hh = (const float*)d_in[3];
  const float* b_ih = (const float*)d_in[4];
  const float* b_hh = (const float*)d_in[5];
  const float* fc_W = (const float*)d_in[6];
  const float* fc_b = (const float*)d_in[7];
  float* out = (float*)d_out;

  // table (32.77 MB) lives in d_out: read only by lstm_mfma, which completes
  // (stream-ordered) before fc_mfma overwrites d_out. h_last in d_ws.
  float* table = out;
  float* hbuf = (float*)d_ws;

  build_table<<<VOCAB / K1_ROWS, 256, 0, stream>>>(emb, W_ih, b_ih, b_hh, table);
  lstm_mfma<<<BATCH / NB, 256, 0, stream>>>(x, table, W_hh, hbuf);
  fc_mfma<<<VOCAB / FCV, 256, 0, stream>>>(hbuf, fc_W, fc_b, out);
}

// Round 7
// 322.172 us; speedup vs baseline: 1.1708x; 1.1708x over previous
//
#include <hip/hip_runtime.h>
#include <cstddef>
#include <cstdint>

#define VOCAB 32000
#define EMB 32
#define HID 64
#define NG 256      // 4*HID
#define BATCH 1024
#define SEQ 512
#define NB 4        // real batch rows per block, mapped to M-rows 0,4,8,12
#define ROWB 72     // halfs per H row: 64 + 8 pad (row stride 144 B)
#define PFD 8       // xg gather prefetch depth (steps ahead)

typedef short short8 __attribute__((ext_vector_type(8)));
typedef _Float16 half8 __attribute__((ext_vector_type(8)));
typedef float floatx4 __attribute__((ext_vector_type(4)));
typedef int int4v __attribute__((ext_vector_type(4)));

union FragH {
  half8 h;
  int4v v;
};

__device__ __forceinline__ float fast_sig(float x) {
  return __builtin_amdgcn_rcpf(1.0f + __expf(-x));
}
__device__ __forceinline__ float fast_tanh(float x) {
  // 1 - 2/(e^{2x}+1); saturates correctly at +-inf via rcp(inf)=0
  return fmaf(-2.0f, __builtin_amdgcn_rcpf(__expf(2.0f * x) + 1.0f), 1.0f);
}

// ---------------- Kernel 1: fused embedding+input-proj table ----------------
// GATE-INTERLEAVED layout: table[v*256 + h*4 + g], g in {i,f,g,o}.
// Thread tid computes gate row gidx = (tid&3)*64 + (tid>>2) so that the WRITE
// at column `tid` stays perfectly coalesced while the layout permutes.
#define K1_ROWS 32
__global__ __launch_bounds__(256) void build_table(
    const float* __restrict__ emb, const float* __restrict__ W_ih,
    const float* __restrict__ b_ih, const float* __restrict__ b_hh,
    float* __restrict__ table) {
  __shared__ __align__(16) float erow[K1_ROWS * EMB];
  const int tid = threadIdx.x;
  const int v0 = blockIdx.x * K1_ROWS;
  const int gidx = (tid & 3) * 64 + (tid >> 2);  // W_ih row this thread owns

  float w[EMB];
#pragma unroll
  for (int e = 0; e < EMB; e += 4) {
    const float4 t = *(const float4*)&W_ih[gidx * EMB + e];
    w[e] = t.x; w[e + 1] = t.y; w[e + 2] = t.z; w[e + 3] = t.w;
  }
  const float bsum = b_ih[gidx] + b_hh[gidx];

  ((float4*)erow)[tid] = ((const float4*)&emb[(size_t)v0 * EMB])[tid];
  __syncthreads();

#pragma unroll 4
  for (int r = 0; r < K1_ROWS; ++r) {
    float acc = bsum;
#pragma unroll
    for (int e = 0; e < EMB; ++e) acc += erow[r * EMB + e] * w[e];
    table[(size_t)(v0 + r) * NG + tid] = acc;  // coalesced; layout is h*4+g
  }
}

// ---------------- Kernel 2: LSTM recurrence via MFMA (fp16 single-product) --
// Grid: BATCH/NB = 256 blocks x 256 threads (4 waves), 1 block/CU.
// Each lane owns exactly one (batch=blk*4+quad, hid=w*16+col) state.
// THIS IS THE R1-EXACT FORM (measured 147.2 us twice). Every restructure of
// the C-operand handling (persistent acc R3: 213, split-K R5: 155, fresh-z4
// R6: 197) regressed -> do not touch the step body.
__global__ __launch_bounds__(256) void lstm_mfma(
    const int* __restrict__ x, const float* __restrict__ table,
    const float* __restrict__ W_hh, float* __restrict__ h_out) {
  __shared__ __align__(16) _Float16 Hs[2][16 * ROWB];  // [buf][row][hid]
  __shared__ int xls[NB * SEQ];

  const int tid = threadIdx.x;
  const int w = tid >> 6;       // wave 0..3
  const int lane = tid & 63;
  const int quad = lane >> 4;   // 0..3 -> owns batch row blk*4+quad (M-row 4*quad)
  const int col = lane & 15;    // MFMA n-col / A m-row
  const int blk = blockIdx.x;
  const int myhid = w * 16 + col;

  // zero H buffers (junk rows read as A must be exactly zero)
  {
    int* hz = (int*)&Hs[0][0];
    const int nz = (int)(sizeof(Hs) / 4);
    for (int i = tid; i < nz; i += 256) hz[i] = 0;
  }
  // stage this block's token ids
  {
    const int* xsrc = &x[(size_t)blk * NB * SEQ];
    for (int i = tid; i < NB * SEQ; i += 256) xls[i] = xsrc[i];
  }

  // resident W_hh fragments (fp16): B[k][n], n = (w+ti*4)*16+col, k = ko*32+quad*8+j
  FragH Bf[4][2];
#pragma unroll
  for (int ti = 0; ti < 4; ++ti) {
    const int n = (w + ti * 4) * 16 + col;
#pragma unroll
    for (int ko = 0; ko < 2; ++ko) {
      const float* src = &W_hh[n * HID + ko * 32 + quad * 8];
#pragma unroll
      for (int j = 0; j < 8; ++j) Bf[ti][ko].h[j] = (_Float16)src[j];
    }
  }

  float c = 0.0f, hcur = 0.0f;

  __syncthreads();  // xls/Hs visible

  const int xrow = quad * SEQ;
  const float* __restrict__ tb4 = table + (size_t)myhid * 4;

  auto gather = [&](int tt) -> float4 {
    return *(const float4*)(tb4 + ((size_t)(unsigned)xls[xrow + tt] << 8));
  };

  // prologue: fill the 8-deep prefetch pipeline
  float4 xg0 = gather(0), xg1 = gather(1), xg2 = gather(2), xg3 = gather(3);
  float4 xg4 = gather(4), xg5 = gather(5), xg6 = gather(6), xg7 = gather(7);

  auto step = [&](float4& XG, const int RB, const int TT) {
    // consume the PFD-step-old gather into temps (vmcnt wait ~0 here),
    // then immediately re-issue this set for step TT+PFD
    const float xi = XG.x, xf = XG.y, xgg = XG.z, xo = XG.w;
    {
      const int tn = (TT + PFD < SEQ) ? TT + PFD : SEQ - 1;
      XG = gather(tn);
    }

    // A fragments: A[m=col][k = ko*32 + quad*8 + j]
    const int abase = col * ROWB + quad * 8;
    FragH A0, A1;
    A0.v = *(const int4v*)&Hs[RB][abase];
    A1.v = *(const int4v*)&Hs[RB][abase + 32];

    floatx4 g4[4];
#pragma unroll
    for (int ti = 0; ti < 4; ++ti) {
      floatx4 a = (floatx4){0.f, 0.f, 0.f, 0.f};
      a = __builtin_amdgcn_mfma_f32_16x16x32_f16(A0.h, Bf[ti][0].h, a, 0, 0, 0);
      a = __builtin_amdgcn_mfma_f32_16x16x32_f16(A1.h, Bf[ti][1].h, a, 0, 0, 0);
      g4[ti] = a;
    }

    // one real state per lane: (batch=blk*4+quad, hid=myhid) at acc reg 0
    {
      const float gi = fast_sig(g4[0][0] + xi);
      const float gf = fast_sig(g4[1][0] + xf);
      const float gg = fast_tanh(g4[2][0] + xgg);
      const float go = fast_sig(g4[3][0] + xo);
      c = gf * c + gi * gg;
      hcur = go * fast_tanh(c);
      Hs[RB ^ 1][(quad * 4) * ROWB + myhid] = (_Float16)hcur;  // M-row 4*quad
    }
    __syncthreads();
  };

  for (int t = 0; t < SEQ; t += 8) {
    step(xg0, 0, t);
    step(xg1, 1, t + 1);
    step(xg2, 0, t + 2);
    step(xg3, 1, t + 3);
    step(xg4, 0, t + 4);
    step(xg5, 1, t + 5);
    step(xg6, 0, t + 6);
    step(xg7, 1, t + 7);
  }

  h_out[((size_t)blk * NB + quad) * HID + myhid] = hcur;
}

// ---------------- Kernel 3: FC to vocab via MFMA (fp16 hi/lo, ~fp32 acc) ----
// out[1024 x 32000] = h[1024 x 64] @ fc_W^T + b. Grid: 250 blocks x 256 thr.
// Each block: 128 vocab cols; wave w owns 32 cols (2 N-tiles of 16).
// fp16 hi/lo error compensation: X = Xh + Xl (both fp16);
//   out = Ah*Bh + Al*Bh + Ah*Bl  (Al*Bl ~ 2^-22, dropped) -> fp32-level acc.
// B fragments resident in regs (fc_W tile read ONCE per block); no LDS.
// M streamed in 64 chunks of 16 batch rows, 1-chunk h-load lookahead.
#define FCV 128
__global__ __launch_bounds__(256, 1) void fc_mfma(
    const float* __restrict__ h, const float* __restrict__ fc_W,
    const float* __restrict__ fc_b, float* __restrict__ out) {
  const int tid = threadIdx.x;
  const int w = tid >> 6;
  const int lane = tid & 63;
  const int q = lane >> 4;
  const int c = lane & 15;
  const int nbase = blockIdx.x * FCV + w * 32;  // + nt*16 + c

  const floatx4 z4 = (floatx4){0.f, 0.f, 0.f, 0.f};

  // resident B fragments: B[k=ko*32+q*8+j][n=nbase+nt*16+c] = fc_W[n][k]
  FragH Bh[2][2], Bl[2][2];
#pragma unroll
  for (int nt = 0; nt < 2; ++nt) {
#pragma unroll
    for (int ko = 0; ko < 2; ++ko) {
      const float* src = &fc_W[(size_t)(nbase + nt * 16 + c) * HID + ko * 32 + q * 8];
#pragma unroll
      for (int j = 0; j < 8; ++j) {
        const float f = src[j];
        const _Float16 hi = (_Float16)f;
        Bh[nt][ko].h[j] = hi;
        Bl[nt][ko].h[j] = (_Float16)(f - (float)hi);
      }
    }
  }
  const float bias0 = fc_b[nbase + c];
  const float bias1 = fc_b[nbase + 16 + c];

  // A-chunk loader: lane (q,c) reads h[row=mc*16+c][k=q*8..+7, +32..]
  auto loadh = [&](int mc, floatx4& a0, floatx4& a1, floatx4& a2, floatx4& a3) {
    const float* hr = &h[(size_t)(mc * 16 + c) * HID + q * 8];
    a0 = *(const floatx4*)hr;
    a1 = *(const floatx4*)(hr + 4);
    a2 = *(const floatx4*)(hr + 32);
    a3 = *(const floatx4*)(hr + 36);
  };

  floatx4 p0, p1, p2, p3, n0, n1, n2, n3;
  loadh(0, p0, p1, p2, p3);

  for (int mc = 0; mc < BATCH / 16; ++mc) {
    if (mc + 1 < BATCH / 16) loadh(mc + 1, n0, n1, n2, n3);

    // build A fragments (hi/lo) from the prefetched chunk
    FragH Ah0, Al0, Ah1, Al1;
#pragma unroll
    for (int j = 0; j < 4; ++j) {
      float f = p0[j];
      _Float16 hi = (_Float16)f;
      Ah0.h[j] = hi; Al0.h[j] = (_Float16)(f - (float)hi);
      f = p1[j]; hi = (_Float16)f;
      Ah0.h[4 + j] = hi; Al0.h[4 + j] = (_Float16)(f - (float)hi);
      f = p2[j]; hi = (_Float16)f;
      Ah1.h[j] = hi; Al1.h[j] = (_Float16)(f - (float)hi);
      f = p3[j]; hi = (_Float16)f;
      Ah1.h[4 + j] = hi; Al1.h[4 + j] = (_Float16)(f - (float)hi);
    }

    // two independent 6-chain MFMA accumulations (nt = 0, 1)
    floatx4 acc0 = __builtin_amdgcn_mfma_f32_16x16x32_f16(Ah0.h, Bh[0][0].h, z4, 0, 0, 0);
    floatx4 acc1 = __builtin_amdgcn_mfma_f32_16x16x32_f16(Ah0.h, Bh[1][0].h, z4, 0, 0, 0);
    acc0 = __builtin_amdgcn_mfma_f32_16x16x32_f16(Ah1.h, Bh[0][1].h, acc0, 0, 0, 0);
    acc1 = __builtin_amdgcn_mfma_f32_16x16x32_f16(Ah1.h, Bh[1][1].h, acc1, 0, 0, 0);
    acc0 = __builtin_amdgcn_mfma_f32_16x16x32_f16(Al0.h, Bh[0][0].h, acc0, 0, 0, 0);
    acc1 = __builtin_amdgcn_mfma_f32_16x16x32_f16(Al0.h, Bh[1][0].h, acc1, 0, 0, 0);
    acc0 = __builtin_amdgcn_mfma_f32_16x16x32_f16(Al1.h, Bh[0][1].h, acc0, 0, 0, 0);
    acc1 = __builtin_amdgcn_mfma_f32_16x16x32_f16(Al1.h, Bh[1][1].h, acc1, 0, 0, 0);
    acc0 = __builtin_amdgcn_mfma_f32_16x16x32_f16(Ah0.h, Bl[0][0].h, acc0, 0, 0, 0);
    acc1 = __builtin_amdgcn_mfma_f32_16x16x32_f16(Ah0.h, Bl[1][0].h, acc1, 0, 0, 0);
    acc0 = __builtin_amdgcn_mfma_f32_16x16x32_f16(Ah1.h, Bl[0][1].h, acc0, 0, 0, 0);
    acc1 = __builtin_amdgcn_mfma_f32_16x16x32_f16(Ah1.h, Bl[1][1].h, acc1, 0, 0, 0);

    // store: C/D layout col=lane&15, row=(lane>>4)*4+reg
#pragma unroll
    for (int r = 0; r < 4; ++r) {
      const size_t row = (size_t)(mc * 16 + q * 4 + r) * VOCAB;
      __builtin_nontemporal_store(acc0[r] + bias0, &out[row + nbase + c]);
      __builtin_nontemporal_store(acc1[r] + bias1, &out[row + nbase + 16 + c]);
    }

    p0 = n0; p1 = n1; p2 = n2; p3 = n3;
  }
}

extern "C" void kernel_launch(void* const* d_in, const int* in_sizes, int n_in,
                              void* d_out, int out_size, void* d_ws, size_t ws_size,
                              hipStream_t stream) {
  const int* x = (const int*)d_in[0];
  const float* emb = (const float*)d_in[1];
  const float* W_ih = (const float*)d_in[2];
  const float* W_hh = (const float*)d_in[3];
  const float* b_ih = (const float*)d_in[4];
  const float* b_hh = (const float*)d_in[5];
  const float* fc_W = (const float*)d_in[6];
  const float* fc_b = (const float*)d_in[7];
  float* out = (float*)d_out;

  // table (32.77 MB) lives in d_out: read only by lstm_mfma, which completes
  // (stream-ordered) before fc_mfma overwrites d_out. h_last in d_ws.
  float* table = out;
  float* hbuf = (float*)d_ws;

  build_table<<<VOCAB / K1_ROWS, 256, 0, stream>>>(emb, W_ih, b_ih, b_hh, table);
  lstm_mfma<<<BATCH / NB, 256, 0, stream>>>(x, table, W_hh, hbuf);
  fc_mfma<<<VOCAB / FCV, 256, 0, stream>>>(hbuf, fc_W, fc_b, out);
}

// Round 8
// 315.916 us; speedup vs baseline: 1.1940x; 1.0198x over previous
//
#include <hip/hip_runtime.h>
#include <cstddef>
#include <cstdint>

#define VOCAB 32000
#define EMB 32
#define HID 64
#define NG 256      // 4*HID
#define BATCH 1024
#define SEQ 512
#define NB 4        // real batch rows per block, mapped to M-rows 0,4,8,12
#define ROWB 72     // halfs per H row: 64 + 8 pad (row stride 144 B)
#define PFD 8       // xg gather prefetch depth (steps ahead)

#define L2E 1.44269504088896340736f  // log2(e)

typedef short short8 __attribute__((ext_vector_type(8)));
typedef _Float16 half8 __attribute__((ext_vector_type(8)));
typedef float floatx4 __attribute__((ext_vector_type(4)));
typedef int int4v __attribute__((ext_vector_type(4)));

union FragH {
  half8 h;
  int4v v;
};

// ---------------- Kernel 1: fused embedding+input-proj table ----------------
// GATE-INTERLEAVED layout: table[v*256 + h*4 + g], g in {i,f,g,o}.
// Thread tid computes gate row gidx = (tid&3)*64 + (tid>>2) so that the WRITE
// at column `tid` stays perfectly coalesced while the layout permutes.
// exp2-FOLDING: stored preactivation is PRE-SCALED per gate type:
//   i,f,o rows: * -log2(e)   (sigmoid(x) = rcp(1+exp2(-L2E*x)))
//   g   row  : * +2log2(e)   (tanh(x)    = 1-2*rcp(exp2(2*L2E*x)+1))
// so the LSTM gate math needs no v_mul before any v_exp_f32.
#define K1_ROWS 32
__global__ __launch_bounds__(256) void build_table(
    const float* __restrict__ emb, const float* __restrict__ W_ih,
    const float* __restrict__ b_ih, const float* __restrict__ b_hh,
    float* __restrict__ table) {
  __shared__ __align__(16) float erow[K1_ROWS * EMB];
  const int tid = threadIdx.x;
  const int v0 = blockIdx.x * K1_ROWS;
  const int gidx = (tid & 3) * 64 + (tid >> 2);  // W_ih row this thread owns
  const float sc = ((tid & 3) == 2) ? (2.0f * L2E) : (-L2E);  // per-gate scale

  float w[EMB];
#pragma unroll
  for (int e = 0; e < EMB; e += 4) {
    const float4 t = *(const float4*)&W_ih[gidx * EMB + e];
    w[e] = t.x; w[e + 1] = t.y; w[e + 2] = t.z; w[e + 3] = t.w;
  }
  const float bsum = b_ih[gidx] + b_hh[gidx];

  ((float4*)erow)[tid] = ((const float4*)&emb[(size_t)v0 * EMB])[tid];
  __syncthreads();

#pragma unroll 4
  for (int r = 0; r < K1_ROWS; ++r) {
    float acc = bsum;
#pragma unroll
    for (int e = 0; e < EMB; ++e) acc += erow[r * EMB + e] * w[e];
    table[(size_t)(v0 + r) * NG + tid] = acc * sc;  // coalesced; layout h*4+g
  }
}

// ---------------- Kernel 2: LSTM recurrence via MFMA (fp16 single-product) --
// Grid: BATCH/NB = 256 blocks x 256 threads (4 waves), 1 block/CU.
// Each lane owns exactly one (batch=blk*4+quad, hid=w*16+col) state.
// BODY = R1-EXACT FORM (147 us, measured 3x). The ONLY changes this round:
//  (1) exp2-folded gate section (table + W_hh fragments pre-scaled; removes
//      the 5 v_mul-by-log2e, two of which sit on the serial gate chain),
//  (2) xls stores pre-shifted byte offsets (drops the per-gather <<8).
// The MFMA/acc structure (fresh zero-init a, 2-chain, post-MFMA xg add,
// __syncthreads) is untouched — every variation of it regressed (R3/R5/R6).
__global__ __launch_bounds__(256) void lstm_mfma(
    const int* __restrict__ x, const float* __restrict__ table,
    const float* __restrict__ W_hh, float* __restrict__ h_out) {
  __shared__ __align__(16) _Float16 Hs[2][16 * ROWB];  // [buf][row][hid]
  __shared__ int xls[NB * SEQ];

  const int tid = threadIdx.x;
  const int w = tid >> 6;       // wave 0..3
  const int lane = tid & 63;
  const int quad = lane >> 4;   // 0..3 -> owns batch row blk*4+quad (M-row 4*quad)
  const int col = lane & 15;    // MFMA n-col / A m-row
  const int blk = blockIdx.x;
  const int myhid = w * 16 + col;

  // zero H buffers (junk rows read as A must be exactly zero)
  {
    int* hz = (int*)&Hs[0][0];
    const int nz = (int)(sizeof(Hs) / 4);
    for (int i = tid; i < nz; i += 256) hz[i] = 0;
  }
  // stage this block's token ids as PRE-SHIFTED byte offsets (tok*1024)
  {
    const int* xsrc = &x[(size_t)blk * NB * SEQ];
    for (int i = tid; i < NB * SEQ; i += 256) xls[i] = xsrc[i] << 10;
  }

  // resident W_hh fragments (fp16, PRE-SCALED per gate type ti):
  // B[k][n], n = (w+ti*4)*16+col, k = ko*32+quad*8+j
  FragH Bf[4][2];
#pragma unroll
  for (int ti = 0; ti < 4; ++ti) {
    const int n = (w + ti * 4) * 16 + col;
    const float sc = (ti == 2) ? (2.0f * L2E) : (-L2E);
#pragma unroll
    for (int ko = 0; ko < 2; ++ko) {
      const float* src = &W_hh[n * HID + ko * 32 + quad * 8];
#pragma unroll
      for (int j = 0; j < 8; ++j) Bf[ti][ko].h[j] = (_Float16)(src[j] * sc);
    }
  }

  float cs = 0.0f, hcur = 0.0f;  // cs = 2*L2E * c (scaled cell state)

  __syncthreads();  // xls/Hs visible

  const int xrow = quad * SEQ;
  const char* __restrict__ tb4 = (const char*)(table + (size_t)myhid * 4);

  auto gather = [&](int tt) -> float4 {
    return *(const float4*)(tb4 + (size_t)(unsigned)xls[xrow + tt]);
  };

  // prologue: fill the 8-deep prefetch pipeline
  float4 xg0 = gather(0), xg1 = gather(1), xg2 = gather(2), xg3 = gather(3);
  float4 xg4 = gather(4), xg5 = gather(5), xg6 = gather(6), xg7 = gather(7);

  auto step = [&](float4& XG, const int RB, const int TT) {
    // consume the PFD-step-old gather into temps (vmcnt wait ~0 here),
    // then immediately re-issue this set for step TT+PFD
    const float xi = XG.x, xf = XG.y, xgg = XG.z, xo = XG.w;
    {
      const int tn = (TT + PFD < SEQ) ? TT + PFD : SEQ - 1;
      XG = gather(tn);
    }

    // A fragments: A[m=col][k = ko*32 + quad*8 + j]
    const int abase = col * ROWB + quad * 8;
    FragH A0, A1;
    A0.v = *(const int4v*)&Hs[RB][abase];
    A1.v = *(const int4v*)&Hs[RB][abase + 32];

    floatx4 g4[4];
#pragma unroll
    for (int ti = 0; ti < 4; ++ti) {
      floatx4 a = (floatx4){0.f, 0.f, 0.f, 0.f};
      a = __builtin_amdgcn_mfma_f32_16x16x32_f16(A0.h, Bf[ti][0].h, a, 0, 0, 0);
      a = __builtin_amdgcn_mfma_f32_16x16x32_f16(A1.h, Bf[ti][1].h, a, 0, 0, 0);
      g4[ti] = a;
    }

    // gates, exp2-folded (preacts arrive pre-scaled; see build_table):
    //   sig -> rcp(1+exp2(y)), y = -L2E*pre
    //   gg2 = 2*L2E*tanh(pre_g) = fma(-4*L2E, rcp(1+exp2(2*L2E*pre_g)), 2*L2E)
    {
      const float gi = __builtin_amdgcn_rcpf(1.0f + __builtin_amdgcn_exp2f(g4[0][0] + xi));
      const float gf = __builtin_amdgcn_rcpf(1.0f + __builtin_amdgcn_exp2f(g4[1][0] + xf));
      const float rg = __builtin_amdgcn_rcpf(1.0f + __builtin_amdgcn_exp2f(g4[2][0] + xgg));
      const float go = __builtin_amdgcn_rcpf(1.0f + __builtin_amdgcn_exp2f(g4[3][0] + xo));
      const float gg2 = fmaf(-4.0f * L2E, rg, 2.0f * L2E);
      cs = fmaf(gi, gg2, gf * cs);  // scaled cell state (2*L2E*c)
      const float rc = __builtin_amdgcn_rcpf(1.0f + __builtin_amdgcn_exp2f(cs));
      hcur = go * fmaf(-2.0f, rc, 1.0f);  // go * tanh(c), unscaled
      Hs[RB ^ 1][(quad * 4) * ROWB + myhid] = (_Float16)hcur;  // M-row 4*quad
    }
    __syncthreads();
  };

  for (int t = 0; t < SEQ; t += 8) {
    step(xg0, 0, t);
    step(xg1, 1, t + 1);
    step(xg2, 0, t + 2);
    step(xg3, 1, t + 3);
    step(xg4, 0, t + 4);
    step(xg5, 1, t + 5);
    step(xg6, 0, t + 6);
    step(xg7, 1, t + 7);
  }

  h_out[((size_t)blk * NB + quad) * HID + myhid] = hcur;
}

// ---------------- Kernel 3: FC to vocab via MFMA (fp16 hi/lo, ~fp32 acc) ----
// out[1024 x 32000] = h[1024 x 64] @ fc_W^T + b. Grid: 250 blocks x 256 thr.
// Each block: 128 vocab cols; wave w owns 32 cols (2 N-tiles of 16).
// fp16 hi/lo error compensation: X = Xh + Xl (both fp16);
//   out = Ah*Bh + Al*Bh + Ah*Bl  (Al*Bl ~ 2^-22, dropped) -> fp32-level acc.
// B fragments resident in regs (fc_W tile read ONCE per block); no LDS.
// M streamed in 64 chunks of 16 batch rows, 1-chunk h-load lookahead.
#define FCV 128
__global__ __launch_bounds__(256, 1) void fc_mfma(
    const float* __restrict__ h, const float* __restrict__ fc_W,
    const float* __restrict__ fc_b, float* __restrict__ out) {
  const int tid = threadIdx.x;
  const int w = tid >> 6;
  const int lane = tid & 63;
  const int q = lane >> 4;
  const int c = lane & 15;
  const int nbase = blockIdx.x * FCV + w * 32;  // + nt*16 + c

  const floatx4 z4 = (floatx4){0.f, 0.f, 0.f, 0.f};

  // resident B fragments: B[k=ko*32+q*8+j][n=nbase+nt*16+c] = fc_W[n][k]
  FragH Bh[2][2], Bl[2][2];
#pragma unroll
  for (int nt = 0; nt < 2; ++nt) {
#pragma unroll
    for (int ko = 0; ko < 2; ++ko) {
      const float* src = &fc_W[(size_t)(nbase + nt * 16 + c) * HID + ko * 32 + q * 8];
#pragma unroll
      for (int j = 0; j < 8; ++j) {
        const float f = src[j];
        const _Float16 hi = (_Float16)f;
        Bh[nt][ko].h[j] = hi;
        Bl[nt][ko].h[j] = (_Float16)(f - (float)hi);
      }
    }
  }
  const float bias0 = fc_b[nbase + c];
  const float bias1 = fc_b[nbase + 16 + c];

  // A-chunk loader: lane (q,c) reads h[row=mc*16+c][k=q*8..+7, +32..]
  auto loadh = [&](int mc, floatx4& a0, floatx4& a1, floatx4& a2, floatx4& a3) {
    const float* hr = &h[(size_t)(mc * 16 + c) * HID + q * 8];
    a0 = *(const floatx4*)hr;
    a1 = *(const floatx4*)(hr + 4);
    a2 = *(const floatx4*)(hr + 32);
    a3 = *(const floatx4*)(hr + 36);
  };

  floatx4 p0, p1, p2, p3, n0, n1, n2, n3;
  loadh(0, p0, p1, p2, p3);

  for (int mc = 0; mc < BATCH / 16; ++mc) {
    if (mc + 1 < BATCH / 16) loadh(mc + 1, n0, n1, n2, n3);

    // build A fragments (hi/lo) from the prefetched chunk
    FragH Ah0, Al0, Ah1, Al1;
#pragma unroll
    for (int j = 0; j < 4; ++j) {
      float f = p0[j];
      _Float16 hi = (_Float16)f;
      Ah0.h[j] = hi; Al0.h[j] = (_Float16)(f - (float)hi);
      f = p1[j]; hi = (_Float16)f;
      Ah0.h[4 + j] = hi; Al0.h[4 + j] = (_Float16)(f - (float)hi);
      f = p2[j]; hi = (_Float16)f;
      Ah1.h[j] = hi; Al1.h[j] = (_Float16)(f - (float)hi);
      f = p3[j]; hi = (_Float16)f;
      Ah1.h[4 + j] = hi; Al1.h[4 + j] = (_Float16)(f - (float)hi);
    }

    // two independent 6-chain MFMA accumulations (nt = 0, 1)
    floatx4 acc0 = __builtin_amdgcn_mfma_f32_16x16x32_f16(Ah0.h, Bh[0][0].h, z4, 0, 0, 0);
    floatx4 acc1 = __builtin_amdgcn_mfma_f32_16x16x32_f16(Ah0.h, Bh[1][0].h, z4, 0, 0, 0);
    acc0 = __builtin_amdgcn_mfma_f32_16x16x32_f16(Ah1.h, Bh[0][1].h, acc0, 0, 0, 0);
    acc1 = __builtin_amdgcn_mfma_f32_16x16x32_f16(Ah1.h, Bh[1][1].h, acc1, 0, 0, 0);
    acc0 = __builtin_amdgcn_mfma_f32_16x16x32_f16(Al0.h, Bh[0][0].h, acc0, 0, 0, 0);
    acc1 = __builtin_amdgcn_mfma_f32_16x16x32_f16(Al0.h, Bh[1][0].h, acc1, 0, 0, 0);
    acc0 = __builtin_amdgcn_mfma_f32_16x16x32_f16(Al1.h, Bh[0][1].h, acc0, 0, 0, 0);
    acc1 = __builtin_amdgcn_mfma_f32_16x16x32_f16(Al1.h, Bh[1][1].h, acc1, 0, 0, 0);
    acc0 = __builtin_amdgcn_mfma_f32_16x16x32_f16(Ah0.h, Bl[0][0].h, acc0, 0, 0, 0);
    acc1 = __builtin_amdgcn_mfma_f32_16x16x32_f16(Ah0.h, Bl[1][0].h, acc1, 0, 0, 0);
    acc0 = __builtin_amdgcn_mfma_f32_16x16x32_f16(Ah1.h, Bl[0][1].h, acc0, 0, 0, 0);
    acc1 = __builtin_amdgcn_mfma_f32_16x16x32_f16(Ah1.h, Bl[1][1].h, acc1, 0, 0, 0);

    // store: C/D layout col=lane&15, row=(lane>>4)*4+reg
#pragma unroll
    for (int r = 0; r < 4; ++r) {
      const size_t row = (size_t)(mc * 16 + q * 4 + r) * VOCAB;
      __builtin_nontemporal_store(acc0[r] + bias0, &out[row + nbase + c]);
      __builtin_nontemporal_store(acc1[r] + bias1, &out[row + nbase + 16 + c]);
    }

    p0 = n0; p1 = n1; p2 = n2; p3 = n3;
  }
}

extern "C" void kernel_launch(void* const* d_in, const int* in_sizes, int n_in,
                              void* d_out, int out_size, void* d_ws, size_t ws_size,
                              hipStream_t stream) {
  const int* x = (const int*)d_in[0];
  const float* emb = (const float*)d_in[1];
  const float* W_ih = (const float*)d_in[2];
  const float* W_hh = (const float*)d_in[3];
  const float* b_ih = (const float*)d_in[4];
  const float* b_hh = (const float*)d_in[5];
  const float* fc_W = (const float*)d_in[6];
  const float* fc_b = (const float*)d_in[7];
  float* out = (float*)d_out;

  // table (32.77 MB) lives in d_out: read only by lstm_mfma, which completes
  // (stream-ordered) before fc_mfma overwrites d_out. h_last in d_ws.
  float* table = out;
  float* hbuf = (float*)d_ws;

  build_table<<<VOCAB / K1_ROWS, 256, 0, stream>>>(emb, W_ih, b_ih, b_hh, table);
  lstm_mfma<<<BATCH / NB, 256, 0, stream>>>(x, table, W_hh, hbuf);
  fc_mfma<<<VOCAB / FCV, 256, 0, stream>>>(hbuf, fc_W, fc_b, out);
}